// Round 10
// baseline (217.325 us; speedup 1.0000x reference)
//
#include <hip/hip_runtime.h>
#include <cmath>

#define GAS __attribute__((address_space(1)))
#define LAS __attribute__((address_space(3)))

typedef __bf16 bf16x8 __attribute__((ext_vector_type(8)));
typedef float f32x4 __attribute__((ext_vector_type(4)));
typedef float f32x16 __attribute__((ext_vector_type(16)));

__device__ __forceinline__ void gload16(const void* g, void* l) {
    __builtin_amdgcn_global_load_lds((const GAS void*)g, (LAS void*)l, 16, 0, 0);
}

// ---- merged prep: fp32->bf16 converts (12928 blk) + transposes (2304 blk) ----
__global__ void k_prep(const float* __restrict__ gnn, const float* __restrict__ tr,
                       const float* __restrict__ Wo, const float* __restrict__ W1,
                       const float* __restrict__ W2, const float* __restrict__ Wg,
                       const float* __restrict__ Wt, const float* __restrict__ Wv,
                       __bf16* __restrict__ X, __bf16* __restrict__ W1ab,
                       __bf16* __restrict__ Wp, __bf16* __restrict__ Wv_b,
                       __bf16* __restrict__ WoT, __bf16* __restrict__ WgT,
                       __bf16* __restrict__ WtT) {
    __shared__ float t[32][33];
    int b = blockIdx.x;
    int tid = threadIdx.x;
    if (b < 12928) {
        const float* src; __bf16* dst; int sld, dld, base, c8;
        if (b < 4096)       { src=gnn;     sld=512;  dst=X+1024;         dld=2304; base=0;     c8=64; }
        else if (b < 10240) { src=tr;      sld=768;  dst=X+1536;         dld=2304; base=4096;  c8=96; }
        else if (b < 10752) { src=W1;      sld=2048; dst=W1ab;           dld=1024; base=10240; c8=128; }
        else if (b < 11264) { src=W1+1024; sld=2048; dst=W1ab+1024*1024; dld=1024; base=10752; c8=128; }
        else if (b < 11776) { src=W2;      sld=1024; dst=Wp;             dld=2304; base=11264; c8=128; }
        else if (b < 12032) { src=Wg;      sld=512;  dst=Wp+1024;        dld=2304; base=11776; c8=64; }
        else if (b < 12416) { src=Wt;      sld=768;  dst=Wp+1536;        dld=2304; base=12032; c8=96; }
        else                { src=Wv;      sld=1024; dst=Wv_b;           dld=1024; base=12416; c8=128; }
        int idx = (b - base) * 256 + tid;
        int r = idx / c8;
        int c = (idx - r * c8) << 3;
        const float4* s = reinterpret_cast<const float4*>(src + (long)r * sld + c);
        float4 x0 = s[0], x1 = s[1];
        bf16x8 v;
        v[0]=(__bf16)x0.x; v[1]=(__bf16)x0.y; v[2]=(__bf16)x0.z; v[3]=(__bf16)x0.w;
        v[4]=(__bf16)x1.x; v[5]=(__bf16)x1.y; v[6]=(__bf16)x1.z; v[7]=(__bf16)x1.w;
        *reinterpret_cast<bf16x8*>(dst + (long)r * dld + c) = v;
    } else {
        int bb = b - 12928;
        const float* src; __bf16* dst; int R, C, tile;
        if (bb < 1024)      { src=Wo; dst=WoT; R=1024; C=1024; tile=bb; }
        else if (bb < 1536) { src=Wg; dst=WgT; R=1024; C=512;  tile=bb-1024; }
        else                { src=Wt; dst=WtT; R=1024; C=768;  tile=bb-1536; }
        int tx_n = C >> 5;
        int c0 = (tile % tx_n) << 5, r0 = (tile / tx_n) << 5;
        int tx = tid & 31, ty = tid >> 5;  // 32 x 8
        #pragma unroll
        for (int i = 0; i < 32; i += 8)
            t[ty + i][tx] = src[(long)(r0 + ty + i) * C + c0 + tx];
        __syncthreads();
        #pragma unroll
        for (int i = 0; i < 32; i += 8)
            dst[(long)(c0 + ty + i) * R + r0 + tx] = (__bf16)t[tx][ty + i];
    }
}

// ---- merged bias dot-products: b_att = Wo@bv + bo; vb_t = Wv@bt; vb_g = Wv@bg
__global__ void k_bias1(const float* __restrict__ Wo, const float* __restrict__ bv,
                        const float* __restrict__ bo, const float* __restrict__ Wv,
                        const float* __restrict__ bt, const float* __restrict__ bg,
                        float* __restrict__ b_att, float* __restrict__ vb_t,
                        float* __restrict__ vb_g) {
    int b = blockIdx.x;
    const float* mat; const float* vec; float* dst; int i; bool addbo = false;
    if (b < 1024)      { mat = Wo; vec = bv; dst = b_att; i = b;        addbo = true; }
    else if (b < 2048) { mat = Wv; vec = bt; dst = vb_t;  i = b - 1024; }
    else               { mat = Wv; vec = bg; dst = vb_g;  i = b - 2048; }
    float s = 0.f;
    for (int k = threadIdx.x; k < 1024; k += 256) s += mat[(long)i * 1024 + k] * vec[k];
    __shared__ float red[256];
    red[threadIdx.x] = s;
    __syncthreads();
    for (int off = 128; off > 0; off >>= 1) {
        if (threadIdx.x < off) red[threadIdx.x] += red[threadIdx.x + off];
        __syncthreads();
    }
    if (threadIdx.x == 0) dst[i] = red[0] + (addbo ? bo[i] : 0.f);
}

// bz2 = b1 + (W1a+W1b)@b_att + U1@vb_t + U2@vb_g ;  b_out = b2 + bg + bt
__global__ void k_bias_z2(const float* __restrict__ W1, const float* __restrict__ b_att,
                          const float* __restrict__ b1, const __bf16* __restrict__ U12,
                          const float* __restrict__ vb_t, const float* __restrict__ vb_g,
                          const float* __restrict__ bt, const float* __restrict__ bg,
                          const float* __restrict__ b2,
                          float* __restrict__ bz2, float* __restrict__ b_out) {
    int i = blockIdx.x;
    float s = 0.f;
    for (int k = threadIdx.x; k < 1024; k += 256) {
        s += (W1[(long)i * 2048 + k] + W1[(long)i * 2048 + 1024 + k]) * b_att[k];
        s += (float)U12[(long)i * 1024 + k] * vb_t[k];
        s += (float)U12[(long)(i + 1024) * 1024 + k] * vb_g[k];
    }
    __shared__ float red[256];
    red[threadIdx.x] = s;
    __syncthreads();
    for (int off = 128; off > 0; off >>= 1) {
        if (threadIdx.x < off) red[threadIdx.x] += red[threadIdx.x + off];
        __syncthreads();
    }
    if (threadIdx.x == 0) {
        bz2[i] = red[0] + b1[i];
        b_out[i] = b2[i] + bg[i] + bt[i];
    }
}

// ---------------- 64x64 NT GEMM body (2-phase, verified r2-r9) ----------------
__device__ __forceinline__ void gemm64_body(
    const __bf16* __restrict__ A, int lda,
    const __bf16* __restrict__ B, int ldb,
    __bf16* __restrict__ C, int ldc,
    int K, int n_tiles, int bid) {
    constexpr int BM = 64, BN = 64, BK = 32;
    constexpr int MR = 2, NR = 2;
    __shared__ alignas(16) __bf16 As[2][BM][BK];
    __shared__ alignas(16) __bf16 Bs[2][BN][BK];

    const int tid = threadIdx.x;
    const int lane = tid & 63;
    const int wave = tid >> 6;
    const int bn = bid % n_tiles;
    const int bm = bid / n_tiles;
    const int m0 = bm * BM, n0 = bn * BN;

    const int rp_l = tid >> 2;
    const int sp = tid & 3;
    const int wr = (wave >> 1) * 32;
    const int wc = (wave & 1) * 32;
    const int fr = lane & 15;
    const int fb = (lane >> 4) << 4;

    f32x4 acc[MR][NR] = {};
    const int nk = K / BK;

    auto stage = [&](int buf, int kt) {
        int rl = (rp_l & ~1) | ((rp_l ^ (rp_l >> 2)) & 1);
        int sl = sp ^ (rl & 3);
        gload16(A + (long)(m0 + rl) * lda + kt * BK + sl * 8, (char*)&As[buf][0][0] + tid * 16);
        gload16(B + (long)(n0 + rl) * ldb + kt * BK + sl * 8, (char*)&Bs[buf][0][0] + tid * 16);
    };

    stage(0, 0);
    for (int kt = 0; kt < nk; ++kt) {
        const int buf = kt & 1;
        __syncthreads();
        if (kt + 1 < nk) stage(buf ^ 1, kt + 1);
        const char* abase = (const char*)&As[buf][0][0];
        const char* bbase = (const char*)&Bs[buf][0][0];
        bf16x8 af[MR], bfr[NR];
        #pragma unroll
        for (int m = 0; m < MR; ++m) {
            int r = wr + m * 16 + fr;
            af[m] = *(const bf16x8*)(abase + (((r << 6) + fb) ^ ((r & 7) << 4)));
        }
        #pragma unroll
        for (int n = 0; n < NR; ++n) {
            int r = wc + n * 16 + fr;
            bfr[n] = *(const bf16x8*)(bbase + (((r << 6) + fb) ^ ((r & 7) << 4)));
        }
        #pragma unroll
        for (int m = 0; m < MR; ++m)
            #pragma unroll
            for (int n = 0; n < NR; ++n)
                acc[m][n] = __builtin_amdgcn_mfma_f32_16x16x32_bf16(af[m], bfr[n], acc[m][n], 0, 0, 0);
    }

    const int r0 = (lane >> 4) << 2;
    #pragma unroll
    for (int n = 0; n < NR; ++n) {
        const int gc = n0 + wc + n * 16 + fr;
        #pragma unroll
        for (int m = 0; m < MR; ++m) {
            const long rbase = (long)(m0 + wr + m * 16 + r0);
            #pragma unroll
            for (int r = 0; r < 4; ++r)
                C[(rbase + r) * ldc + gc] = (__bf16)acc[m][n][r];
        }
    }
}

// level-1 batched: U12 = [W1a;W1b]@Wo (512) | VtT = WtT@Wv^T (192) | VgT = WgT@Wv^T (128)
__global__ __launch_bounds__(256, 2) void k_gemmL1(
    const __bf16* __restrict__ W1ab, const __bf16* __restrict__ WoT,
    const __bf16* __restrict__ WtT, const __bf16* __restrict__ WgT,
    const __bf16* __restrict__ Wv_b, __bf16* __restrict__ U12,
    __bf16* __restrict__ VtT, __bf16* __restrict__ VgT) {
    int b = blockIdx.x;
    if (b < 512)      gemm64_body(W1ab, 1024, WoT, 1024, U12, 1024, 1024, 16, b);
    else if (b < 704) gemm64_body(WtT, 1024, Wv_b, 1024, VtT, 1024, 1024, 16, b - 512);
    else              gemm64_body(WgT, 1024, Wv_b, 1024, VgT, 1024, 1024, 16, b - 704);
}

// level-2 batched: Mt = U1@VtT^T -> M1[:,GD:] (192) | Mg = U2@VgT^T -> M1[:,0:GD] (128)
__global__ __launch_bounds__(256, 2) void k_gemmL2(
    const __bf16* __restrict__ U12, const __bf16* __restrict__ VtT,
    const __bf16* __restrict__ VgT, __bf16* __restrict__ M1) {
    int b = blockIdx.x;
    if (b < 192) gemm64_body(U12, 1024, VtT, 1024, M1 + 512, 1280, 1024, 12, b);
    else         gemm64_body(U12 + 1024 * 1024, 1024, VgT, 1024, M1, 1280, 1024, 8, b - 192);
}

// ---- 8-phase 256x256 NT GEMM, frag-major LDS, 32x32x16 MFMA, register ----
// ---- read-ahead: phase P = {stage; [vmcnt]; RD frags for P+1; pin; barrier;
//      MFMA on P's frags (read at P-1, counted lgkmcnt lets P's reads fly)}.
// Conflict-free LDS (r6) + one-phase read-ahead: ~500cyc LDS drain hides under
// the 621cyc MFMA window. A-frags double-buffered af[2][..]; B reuses bfr[kk].
// vmcnt ledger (cross-wave rule: covering drain >=1 barrier before the read):
// prologue VMC4; loop P3 VMC6, P4 VMC4, P7 VMC6, P8 VMC4; last iter VMC0@P3.
// Verified phase-by-phase: every RD region drained+barriered; WAR gaps >=2
// phases (reader's MFMA lgkm-drains before the barrier preceding overwrite).
// MODE 1: +bias, GELU (tanh-form), bf16 out; MODE 2: +bias, fp32 out.
template <int MODE>
__device__ __forceinline__ void gemm8_body(
    const __bf16* __restrict__ A, int lda,
    const __bf16* __restrict__ B, int ldb,
    void* __restrict__ Cv, int ldc,
    const float* __restrict__ bias,
    int K, int n_tiles) {
    __shared__ char lds[131072];

    const int tid = threadIdx.x;
    const int lane = tid & 63;
    const int wave = tid >> 6;
    const int wm = wave >> 2;   // 0..1 -> 128 M-rows
    const int wn = wave & 3;    // 0..3 -> 64 N-cols

    int bid = blockIdx.x;
    const int nwg = gridDim.x;
    if ((nwg & 7) == 0) bid = (bid & 7) * (nwg >> 3) + (bid >> 3);
    const int bn = bid % n_tiles;
    const int bm = bid / n_tiles;
    const int m0 = bm * 256, n0 = bn * 256;

    // staging source map (frag-major; unchanged from r6/r9)
    const int rowA = ((tid >> 7) << 4) + (tid & 15);
    const int colA = (((tid >> 6) & 1) << 5) + (((tid >> 4) & 3) << 3);
    const int rowB = ((tid >> 6) << 4) + (tid & 15);
    const int colB = (((tid >> 4) & 3) << 3);
    const __bf16* Ag = A + (long)(m0 + rowA) * lda + colA;
    const __bf16* Bg = B + (long)(n0 + rowB) * ldb + colB;
    const int tid16 = tid * 16;

    // 32x32 fragment lane addressing within the 1KB-frag-major LDS
    const int laneA = ((lane >> 4) & 1) * 2048 + (lane >> 5) * 256 + (lane & 15) * 16;
    const int laneB = ((lane >> 4) & 1) * 1024 + (lane >> 5) * 256 + (lane & 15) * 16;
    const int bnh = wn >> 1;
    const int bno = (wn & 1) * 4096;

    f32x16 acc[4][2] = {};    // [qh*2+fm][fn], 128 AGPR
    bf16x8 af[2][2][2];       // [set][fm][h] — double-buffered (read-ahead)
    bf16x8 bfr[2][2][2];      // [kk][h][fn]  — kk-alternation is the dbuf

    const int nk = K >> 6;
    const int NI = nk >> 1;

#define STAGE_A(PAR, KT, MH, QH) \
    gload16(Ag + (long)(KT) * 64 + (long)((MH) * 128 + (QH) * 64) * lda, \
            lds + (PAR) * 32768 + (MH) * 16384 + (QH) * 8192 + tid16)
#define STAGE_B(PAR, KT, NH, KK) \
    gload16(Bg + (long)(KT) * 64 + (KK) * 32 + (long)((NH) * 128) * ldb, \
            lds + 65536 + (PAR) * 32768 + (NH) * 16384 + (KK) * 8192 + tid16)
#define VMC6 asm volatile("s_waitcnt vmcnt(6)" ::: "memory")
#define VMC4 asm volatile("s_waitcnt vmcnt(4)" ::: "memory")
#define VMC0 asm volatile("s_waitcnt vmcnt(0)" ::: "memory")
#define BAR  __builtin_amdgcn_s_barrier()
#define PIN  __builtin_amdgcn_sched_barrier(0)
#define RD_A32(S, PAR, QH, KK) { \
        const char* a_ = lds + (PAR) * 32768 + wm * 16384 + (QH) * 8192 + (KK) * 1024; \
        _Pragma("unroll") \
        for (int fm_ = 0; fm_ < 2; ++fm_) { \
            _Pragma("unroll") \
            for (int h_ = 0; h_ < 2; ++h_) \
                af[S][fm_][h_] = *(const bf16x8*)(a_ + fm_ * 4096 + h_ * 512 + laneA); } }
#define RD_B32(KK, PAR) { \
        const char* b_ = lds + 65536 + (PAR) * 32768 + bnh * 16384 + (KK) * 8192 + bno; \
        _Pragma("unroll") \
        for (int fn_ = 0; fn_ < 2; ++fn_) { \
            _Pragma("unroll") \
            for (int h_ = 0; h_ < 2; ++h_) \
                bfr[KK][h_][fn_] = *(const bf16x8*)(b_ + fn_ * 2048 + h_ * 512 + laneB); } }
#define MFMA8(S, QH, KK) { \
        __builtin_amdgcn_s_setprio(1); \
        _Pragma("unroll") \
        for (int h_ = 0; h_ < 2; ++h_) { \
            _Pragma("unroll") \
            for (int fm_ = 0; fm_ < 2; ++fm_) { \
                _Pragma("unroll") \
                for (int fn_ = 0; fn_ < 2; ++fn_) \
                    acc[(QH) * 2 + fm_][fn_] = __builtin_amdgcn_mfma_f32_32x32x16_bf16( \
                        af[S][fm_][h_], bfr[KK][h_][fn_], acc[(QH) * 2 + fm_][fn_], 0, 0, 0); } } \
        __builtin_amdgcn_s_setprio(0); }

    // prologue: t0 fully + t1.{A q0, B k0} (12 gloads); VMC4 drains t0 entirely
    // (incl. B k1) leaving 4 = {A' q0, B' k0}; BAR; initial RD for P1.
    STAGE_A(0, 0, 0, 0); STAGE_A(0, 0, 1, 0);
    STAGE_B(0, 0, 0, 0); STAGE_B(0, 0, 1, 0);
    STAGE_A(0, 0, 0, 1); STAGE_A(0, 0, 1, 1);
    STAGE_B(0, 0, 0, 1); STAGE_B(0, 0, 1, 1);
    STAGE_A(1, 1, 0, 0); STAGE_A(1, 1, 1, 0);
    STAGE_B(1, 1, 0, 0); STAGE_B(1, 1, 1, 0);
    VMC4;
    BAR;
    RD_B32(0, 0); RD_A32(0, 0, 0, 0);

    for (int I = 0; I < NI; ++I) {
        const int t = 2 * I;
        const bool nl = (I + 1 < NI);
        // P1: MFMA (par0,q0,k0) set0 | RA: B(par0,k1)->bfr1, A(par0,q0,k1)->set1
        STAGE_A(1, t + 1, 0, 1); STAGE_A(1, t + 1, 1, 1);
        RD_B32(1, 0); RD_A32(1, 0, 0, 1); PIN;
        BAR; MFMA8(0, 0, 0); BAR;
        // P2: MFMA (q0,k1) set1 | RA: A(par0,q1,k0)->set0
        STAGE_B(1, t + 1, 0, 1); STAGE_B(1, t + 1, 1, 1);
        RD_A32(0, 0, 1, 0); PIN;
        BAR; MFMA8(1, 0, 1); BAR;
        // P3: MFMA (q1,k0) set0 | RA: A(par0,q1,k1)->set1
        if (nl) { STAGE_A(0, t + 2, 0, 0); STAGE_A(0, t + 2, 1, 0); VMC6; } else { VMC0; }
        RD_A32(1, 0, 1, 1); PIN;
        BAR; MFMA8(0, 1, 0); BAR;
        // P4: MFMA (q1,k1) set1 | RA: B(par1,k0)->bfr0, A(par1,q0,k0)->set0
        if (nl) { STAGE_B(0, t + 2, 0, 0); STAGE_B(0, t + 2, 1, 0); VMC4; }
        RD_B32(0, 1); RD_A32(0, 1, 0, 0); PIN;
        BAR; MFMA8(1, 1, 1); BAR;
        // P5: MFMA (par1,q0,k0) set0 | RA: B(par1,k1)->bfr1, A(par1,q0,k1)->set1
        if (nl) { STAGE_A(0, t + 2, 0, 1); STAGE_A(0, t + 2, 1, 1); }
        RD_B32(1, 1); RD_A32(1, 1, 0, 1); PIN;
        BAR; MFMA8(0, 0, 0); BAR;
        // P6: MFMA (q0,k1) set1 | RA: A(par1,q1,k0)->set0
        if (nl) { STAGE_B(0, t + 2, 0, 1); STAGE_B(0, t + 2, 1, 1); }
        RD_A32(0, 1, 1, 0); PIN;
        BAR; MFMA8(1, 0, 1); BAR;
        // P7: MFMA (q1,k0) set0 | RA: A(par1,q1,k1)->set1
        if (nl) { STAGE_A(1, t + 3, 0, 0); STAGE_A(1, t + 3, 1, 0); VMC6; }
        RD_A32(1, 1, 1, 1); PIN;
        BAR; MFMA8(0, 1, 0); BAR;
        // P8: MFMA (q1,k1) set1 | RA (next iter P1): B(par0,k0)->bfr0, A(par0,q0,k0)->set0
        if (nl) {
            STAGE_B(1, t + 3, 0, 0); STAGE_B(1, t + 3, 1, 0); VMC4;
            RD_B32(0, 0); RD_A32(0, 0, 0, 0);
        }
        PIN;
        BAR; MFMA8(1, 1, 1); BAR;
    }
#undef MFMA8
#undef RD_B32
#undef RD_A32
#undef PIN
#undef BAR
#undef VMC0
#undef VMC4
#undef VMC6
#undef STAGE_B
#undef STAGE_A

    // ---- epilogue: per-wave LDS remap (32 rows x 272B) -> coalesced stores
    // 32x32 C/D: col = lane&31, row = (reg&3) + 8*(reg>>2) + 4*(lane>>5)
    char* scr = lds + wave * 16384;
    const int col32 = lane & 31;
    const int rb5 = (lane >> 5) << 2;
    float bval[2];
    bval[0] = bias ? bias[n0 + wn * 64 + col32] : 0.0f;
    bval[1] = bias ? bias[n0 + wn * 64 + 32 + col32] : 0.0f;

    #pragma unroll
    for (int FM = 0; FM < 4; ++FM) {
        #pragma unroll
        for (int fn_ = 0; fn_ < 2; ++fn_) {
            #pragma unroll
            for (int rg = 0; rg < 16; ++rg) {
                float v = acc[FM][fn_][rg] + bval[fn_];
                if (MODE == 1) {
                    float u = v * (0.7978845608f + 0.0356774081f * v * v);
                    float e = __expf(-2.0f * fabsf(u));
                    float th = (1.0f - e) / (1.0f + e);
                    th = copysignf(th, u);
                    v = 0.5f * v * (1.0f + th);
                }
                int srow = (rg & 3) + ((rg >> 2) << 3) + rb5;
                *(float*)(scr + srow * 272 + (fn_ * 32 + col32) * 4) = v;
            }
        }
        asm volatile("s_waitcnt lgkmcnt(0)" ::: "memory");  // scratch RAW
        if (MODE == 2) {
            #pragma unroll
            for (int rep = 0; rep < 8; ++rep) {
                int row = rep * 4 + (lane >> 4);
                f32x4 val = *(const f32x4*)(scr + row * 272 + (lane & 15) * 16);
                long grow = (long)(m0 + wm * 128 + FM * 32 + row);
                *(f32x4*)&((float*)Cv)[grow * ldc + n0 + wn * 64 + (lane & 15) * 4] = val;
            }
        } else {
            #pragma unroll
            for (int rep = 0; rep < 4; ++rep) {
                int row = rep * 8 + (lane >> 3);
                f32x4 v0 = *(const f32x4*)(scr + row * 272 + (lane & 7) * 32);
                f32x4 v1 = *(const f32x4*)(scr + row * 272 + (lane & 7) * 32 + 16);
                bf16x8 o;
                o[0] = (__bf16)v0[0]; o[1] = (__bf16)v0[1]; o[2] = (__bf16)v0[2]; o[3] = (__bf16)v0[3];
                o[4] = (__bf16)v1[0]; o[5] = (__bf16)v1[1]; o[6] = (__bf16)v1[2]; o[7] = (__bf16)v1[3];
                long grow = (long)(m0 + wm * 128 + FM * 32 + row);
                *(bf16x8*)&((__bf16*)Cv)[grow * ldc + n0 + wn * 64 + (lane & 7) * 8] = o;
            }
        }
        asm volatile("s_waitcnt lgkmcnt(0)" ::: "memory");  // scratch WAR before next FM
    }
}

__global__ __launch_bounds__(512, 2) void k_g256_gelu(
    const __bf16* __restrict__ A, int lda, const __bf16* __restrict__ B, int ldb,
    void* __restrict__ Cv, int ldc, const float* __restrict__ bias, int K, int n_tiles) {
    gemm8_body<1>(A, lda, B, ldb, Cv, ldc, bias, K, n_tiles);
}
__global__ __launch_bounds__(512, 2) void k_g256_out(
    const __bf16* __restrict__ A, int lda, const __bf16* __restrict__ B, int ldb,
    void* __restrict__ Cv, int ldc, const float* __restrict__ bias, int K, int n_tiles) {
    gemm8_body<2>(A, lda, B, ldb, Cv, ldc, bias, K, n_tiles);
}

// ---------------- host ----------------
extern "C" void kernel_launch(void* const* d_in, const int* in_sizes, int n_in,
                              void* d_out, int out_size, void* d_ws, size_t ws_size,
                              hipStream_t stream) {
    constexpr int Bsz = 16384, F = 1024, GD = 512, TD = 768;
    constexpr int XLD = F + GD + TD;  // 2304

    const float* gnn = (const float*)d_in[0];
    const float* tr  = (const float*)d_in[1];
    const float* Wg  = (const float*)d_in[2];
    const float* bg  = (const float*)d_in[3];
    const float* Wt  = (const float*)d_in[4];
    const float* bt  = (const float*)d_in[5];
    const float* Wv  = (const float*)d_in[6];
    const float* bv  = (const float*)d_in[7];
    const float* Wo  = (const float*)d_in[8];
    const float* bo  = (const float*)d_in[9];
    const float* W1  = (const float*)d_in[10];
    const float* b1  = (const float*)d_in[11];
    const float* W2  = (const float*)d_in[12];
    const float* b2  = (const float*)d_in[13];
    float* out = (float*)d_out;

    char* w = (char*)d_ws;
    auto alloc = [&](size_t bytes) {
        char* p = w;
        w += (bytes + 255) & ~(size_t)255;
        return p;
    };
    __bf16* X    = (__bf16*)alloc((size_t)Bsz * XLD * 2);       // [h | gnn | tr]
    __bf16* M1   = (__bf16*)alloc((size_t)F * (GD + TD) * 2);   // [Mg | Mt]
    __bf16* Wp   = (__bf16*)alloc((size_t)F * XLD * 2);         // [W2 | Wg | Wt]
    __bf16* W1ab = (__bf16*)alloc((size_t)2 * F * F * 2);       // [W1a ; W1b]
    __bf16* Wv_b = (__bf16*)alloc((size_t)F * F * 2);
    __bf16* WoT  = (__bf16*)alloc((size_t)F * F * 2);
    __bf16* WgT  = (__bf16*)alloc((size_t)GD * F * 2);
    __bf16* WtT  = (__bf16*)alloc((size_t)TD * F * 2);
    __bf16* U12  = (__bf16*)alloc((size_t)2 * F * F * 2);       // [U1 ; U2]
    __bf16* VtT  = (__bf16*)alloc((size_t)TD * F * 2);
    __bf16* VgT  = (__bf16*)alloc((size_t)GD * F * 2);
    float* b_att = (float*)alloc(F * 4);
    float* vb_t  = (float*)alloc(F * 4);
    float* vb_g  = (float*)alloc(F * 4);
    float* bz2   = (float*)alloc(F * 4);
    float* b_out = (float*)alloc(F * 4);
    if ((size_t)(w - (char*)d_ws) > ws_size) return;

    dim3 b256(256);

    // all converts + transposes, one launch
    k_prep<<<dim3(15232), b256, 0, stream>>>(gnn, tr, Wo, W1, W2, Wg, Wt, Wv,
                                             X, W1ab, Wp, Wv_b, WoT, WgT, WtT);
    // all bias dot-products, one launch (inputs only)
    k_bias1<<<dim3(3072), b256, 0, stream>>>(Wo, bv, bo, Wv, bt, bg, b_att, vb_t, vb_g);

    // level-1 weight composition (4 GEMMs batched)
    k_gemmL1<<<dim3(832), b256, 0, stream>>>(W1ab, WoT, WtT, WgT, Wv_b, U12, VtT, VgT);

    // bz2 from U12
    k_bias_z2<<<dim3(F), b256, 0, stream>>>(W1, b_att, b1, U12, vb_t, vb_g, bt, bg, b2,
                                            bz2, b_out);

    // level-2 weight composition (2 GEMMs batched) -> M1
    k_gemmL2<<<dim3(320), b256, 0, stream>>>(U12, VtT, VgT, M1);

    // pass 1: h = gelu([gnn|tr] @ M1^T + bz2) -> X[:, 0:1024] (bf16)   K=1280
    k_g256_gelu<<<dim3((Bsz / 256) * (F / 256)), dim3(512), 0, stream>>>(
        X + F, XLD, M1, GD + TD, X, XLD, bz2, GD + TD, F / 256);

    // pass 2: out = [h|gnn|tr] @ [W2|Wg|Wt]^T + b_out (fp32)           K=2304
    k_g256_out<<<dim3((Bsz / 256) * (F / 256)), dim3(512), 0, stream>>>(
        X, XLD, Wp, XLD, out, F, b_out, XLD, F / 256);
}

// Round 11
// 216.987 us; speedup vs baseline: 1.0016x; 1.0016x over previous
//
#include <hip/hip_runtime.h>
#include <cmath>

#define GAS __attribute__((address_space(1)))
#define LAS __attribute__((address_space(3)))

typedef __bf16 bf16x8 __attribute__((ext_vector_type(8)));
typedef float f32x4 __attribute__((ext_vector_type(4)));
typedef float f32x16 __attribute__((ext_vector_type(16)));

__device__ __forceinline__ void gload16(const void* g, void* l) {
    __builtin_amdgcn_global_load_lds((const GAS void*)g, (LAS void*)l, 16, 0, 0);
}

// ---- merged prep: fp32->bf16 converts (12928 blk) + transposes (2304 blk) ----
__global__ void k_prep(const float* __restrict__ gnn, const float* __restrict__ tr,
                       const float* __restrict__ Wo, const float* __restrict__ W1,
                       const float* __restrict__ W2, const float* __restrict__ Wg,
                       const float* __restrict__ Wt, const float* __restrict__ Wv,
                       __bf16* __restrict__ X, __bf16* __restrict__ W1ab,
                       __bf16* __restrict__ Wp, __bf16* __restrict__ Wv_b,
                       __bf16* __restrict__ WoT, __bf16* __restrict__ WgT,
                       __bf16* __restrict__ WtT) {
    __shared__ float t[32][33];
    int b = blockIdx.x;
    int tid = threadIdx.x;
    if (b < 12928) {
        const float* src; __bf16* dst; int sld, dld, base, c8;
        if (b < 4096)       { src=gnn;     sld=512;  dst=X+1024;         dld=2304; base=0;     c8=64; }
        else if (b < 10240) { src=tr;      sld=768;  dst=X+1536;         dld=2304; base=4096;  c8=96; }
        else if (b < 10752) { src=W1;      sld=2048; dst=W1ab;           dld=1024; base=10240; c8=128; }
        else if (b < 11264) { src=W1+1024; sld=2048; dst=W1ab+1024*1024; dld=1024; base=10752; c8=128; }
        else if (b < 11776) { src=W2;      sld=1024; dst=Wp;             dld=2304; base=11264; c8=128; }
        else if (b < 12032) { src=Wg;      sld=512;  dst=Wp+1024;        dld=2304; base=11776; c8=64; }
        else if (b < 12416) { src=Wt;      sld=768;  dst=Wp+1536;       dld=2304; base=12032; c8=96; }
        else                { src=Wv;      sld=1024; dst=Wv_b;           dld=1024; base=12416; c8=128; }
        int idx = (b - base) * 256 + tid;
        int r = idx / c8;
        int c = (idx - r * c8) << 3;
        const float4* s = reinterpret_cast<const float4*>(src + (long)r * sld + c);
        float4 x0 = s[0], x1 = s[1];
        bf16x8 v;
        v[0]=(__bf16)x0.x; v[1]=(__bf16)x0.y; v[2]=(__bf16)x0.z; v[3]=(__bf16)x0.w;
        v[4]=(__bf16)x1.x; v[5]=(__bf16)x1.y; v[6]=(__bf16)x1.z; v[7]=(__bf16)x1.w;
        *reinterpret_cast<bf16x8*>(dst + (long)r * dld + c) = v;
    } else {
        int bb = b - 12928;
        const float* src; __bf16* dst; int R, C, tile;
        if (bb < 1024)      { src=Wo; dst=WoT; R=1024; C=1024; tile=bb; }
        else if (bb < 1536) { src=Wg; dst=WgT; R=1024; C=512;  tile=bb-1024; }
        else                { src=Wt; dst=WtT; R=1024; C=768;  tile=bb-1536; }
        int tx_n = C >> 5;
        int c0 = (tile % tx_n) << 5, r0 = (tile / tx_n) << 5;
        int tx = tid & 31, ty = tid >> 5;  // 32 x 8
        #pragma unroll
        for (int i = 0; i < 32; i += 8)
            t[ty + i][tx] = src[(long)(r0 + ty + i) * C + c0 + tx];
        __syncthreads();
        #pragma unroll
        for (int i = 0; i < 32; i += 8)
            dst[(long)(c0 + ty + i) * R + r0 + tx] = (__bf16)t[tx][ty + i];
    }
}

// ---- merged bias dot-products: b_att = Wo@bv + bo; vb_t = Wv@bt; vb_g = Wv@bg
__global__ void k_bias1(const float* __restrict__ Wo, const float* __restrict__ bv,
                        const float* __restrict__ bo, const float* __restrict__ Wv,
                        const float* __restrict__ bt, const float* __restrict__ bg,
                        float* __restrict__ b_att, float* __restrict__ vb_t,
                        float* __restrict__ vb_g) {
    int b = blockIdx.x;
    const float* mat; const float* vec; float* dst; int i; bool addbo = false;
    if (b < 1024)      { mat = Wo; vec = bv; dst = b_att; i = b;        addbo = true; }
    else if (b < 2048) { mat = Wv; vec = bt; dst = vb_t;  i = b - 1024; }
    else               { mat = Wv; vec = bg; dst = vb_g;  i = b - 2048; }
    float s = 0.f;
    for (int k = threadIdx.x; k < 1024; k += 256) s += mat[(long)i * 1024 + k] * vec[k];
    __shared__ float red[256];
    red[threadIdx.x] = s;
    __syncthreads();
    for (int off = 128; off > 0; off >>= 1) {
        if (threadIdx.x < off) red[threadIdx.x] += red[threadIdx.x + off];
        __syncthreads();
    }
    if (threadIdx.x == 0) dst[i] = red[0] + (addbo ? bo[i] : 0.f);
}

// bz2 = b1 + (W1a+W1b)@b_att + U1@vb_t + U2@vb_g ;  b_out = b2 + bg + bt
__global__ void k_bias_z2(const float* __restrict__ W1, const float* __restrict__ b_att,
                          const float* __restrict__ b1, const __bf16* __restrict__ U12,
                          const float* __restrict__ vb_t, const float* __restrict__ vb_g,
                          const float* __restrict__ bt, const float* __restrict__ bg,
                          const float* __restrict__ b2,
                          float* __restrict__ bz2, float* __restrict__ b_out) {
    int i = blockIdx.x;
    float s = 0.f;
    for (int k = threadIdx.x; k < 1024; k += 256) {
        s += (W1[(long)i * 2048 + k] + W1[(long)i * 2048 + 1024 + k]) * b_att[k];
        s += (float)U12[(long)i * 1024 + k] * vb_t[k];
        s += (float)U12[(long)(i + 1024) * 1024 + k] * vb_g[k];
    }
    __shared__ float red[256];
    red[threadIdx.x] = s;
    __syncthreads();
    for (int off = 128; off > 0; off >>= 1) {
        if (threadIdx.x < off) red[threadIdx.x] += red[threadIdx.x + off];
        __syncthreads();
    }
    if (threadIdx.x == 0) {
        bz2[i] = red[0] + b1[i];
        b_out[i] = b2[i] + bg[i] + bt[i];
    }
}

// ---------------- 64x64 NT GEMM body (2-phase, verified r2-r10) ----------------
__device__ __forceinline__ void gemm64_body(
    const __bf16* __restrict__ A, int lda,
    const __bf16* __restrict__ B, int ldb,
    __bf16* __restrict__ C, int ldc,
    int K, int n_tiles, int bid) {
    constexpr int BM = 64, BN = 64, BK = 32;
    constexpr int MR = 2, NR = 2;
    __shared__ alignas(16) __bf16 As[2][BM][BK];
    __shared__ alignas(16) __bf16 Bs[2][BN][BK];

    const int tid = threadIdx.x;
    const int lane = tid & 63;
    const int wave = tid >> 6;
    const int bn = bid % n_tiles;
    const int bm = bid / n_tiles;
    const int m0 = bm * BM, n0 = bn * BN;

    const int rp_l = tid >> 2;
    const int sp = tid & 3;
    const int wr = (wave >> 1) * 32;
    const int wc = (wave & 1) * 32;
    const int fr = lane & 15;
    const int fb = (lane >> 4) << 4;

    f32x4 acc[MR][NR] = {};
    const int nk = K / BK;

    auto stage = [&](int buf, int kt) {
        int rl = (rp_l & ~1) | ((rp_l ^ (rp_l >> 2)) & 1);
        int sl = sp ^ (rl & 3);
        gload16(A + (long)(m0 + rl) * lda + kt * BK + sl * 8, (char*)&As[buf][0][0] + tid * 16);
        gload16(B + (long)(n0 + rl) * ldb + kt * BK + sl * 8, (char*)&Bs[buf][0][0] + tid * 16);
    };

    stage(0, 0);
    for (int kt = 0; kt < nk; ++kt) {
        const int buf = kt & 1;
        __syncthreads();
        if (kt + 1 < nk) stage(buf ^ 1, kt + 1);
        const char* abase = (const char*)&As[buf][0][0];
        const char* bbase = (const char*)&Bs[buf][0][0];
        bf16x8 af[MR], bfr[NR];
        #pragma unroll
        for (int m = 0; m < MR; ++m) {
            int r = wr + m * 16 + fr;
            af[m] = *(const bf16x8*)(abase + (((r << 6) + fb) ^ ((r & 7) << 4)));
        }
        #pragma unroll
        for (int n = 0; n < NR; ++n) {
            int r = wc + n * 16 + fr;
            bfr[n] = *(const bf16x8*)(bbase + (((r << 6) + fb) ^ ((r & 7) << 4)));
        }
        #pragma unroll
        for (int m = 0; m < MR; ++m)
            #pragma unroll
            for (int n = 0; n < NR; ++n)
                acc[m][n] = __builtin_amdgcn_mfma_f32_16x16x32_bf16(af[m], bfr[n], acc[m][n], 0, 0, 0);
    }

    const int r0 = (lane >> 4) << 2;
    #pragma unroll
    for (int n = 0; n < NR; ++n) {
        const int gc = n0 + wc + n * 16 + fr;
        #pragma unroll
        for (int m = 0; m < MR; ++m) {
            const long rbase = (long)(m0 + wr + m * 16 + r0);
            #pragma unroll
            for (int r = 0; r < 4; ++r)
                C[(rbase + r) * ldc + gc] = (__bf16)acc[m][n][r];
        }
    }
}

// level-1 batched: U12 = [W1a;W1b]@Wo (512) | VtT = WtT@Wv^T (192) | VgT = WgT@Wv^T (128)
__global__ __launch_bounds__(256, 2) void k_gemmL1(
    const __bf16* __restrict__ W1ab, const __bf16* __restrict__ WoT,
    const __bf16* __restrict__ WtT, const __bf16* __restrict__ WgT,
    const __bf16* __restrict__ Wv_b, __bf16* __restrict__ U12,
    __bf16* __restrict__ VtT, __bf16* __restrict__ VgT) {
    int b = blockIdx.x;
    if (b < 512)      gemm64_body(W1ab, 1024, WoT, 1024, U12, 1024, 1024, 16, b);
    else if (b < 704) gemm64_body(WtT, 1024, Wv_b, 1024, VtT, 1024, 1024, 16, b - 512);
    else              gemm64_body(WgT, 1024, Wv_b, 1024, VgT, 1024, 1024, 16, b - 704);
}

// level-2 batched: Mt = U1@VtT^T -> M1[:,GD:] (192) | Mg = U2@VgT^T -> M1[:,0:GD] (128)
__global__ __launch_bounds__(256, 2) void k_gemmL2(
    const __bf16* __restrict__ U12, const __bf16* __restrict__ VtT,
    const __bf16* __restrict__ VgT, __bf16* __restrict__ M1) {
    int b = blockIdx.x;
    if (b < 192) gemm64_body(U12, 1024, VtT, 1024, M1 + 512, 1280, 1024, 12, b);
    else         gemm64_body(U12 + 1024 * 1024, 1024, VgT, 1024, M1, 1280, 1024, 8, b - 192);
}

// ---- 8-phase 256x256 NT GEMM, frag-major LDS, 32x32x16 MFMA, T4 deep-prefetch ----
// m201 phase shape: {reads (this phase's frags); stage 1 pair; [VMC6 at P4/P8
// ONLY]; barrier; lgkmcnt(0); setprio MFMA setprio; barrier}. Exactly 2 counted
// drains per iteration, 3 stage-pairs in flight, stage->read distance 5-7 phases
// (>=4000 cyc >> 900-cyc HBM latency, vs r3-r10's distance-2 vmcnt(4) drains).
// Stage slots: P1=A(p1,q1,t+1), P2=B(p0,k0,t+2), P3=A(p0,q0,t+2),
// P4=B(p0,k1,t+2)+VMC6, P5=A(p0,q1,t+2), P6=B(p1,k0,t+3), P7=A(p1,q0,t+3),
// P8=B(p1,k1,t+3)+VMC6.  Ledger verified: drain-leave-6 sets are {P2,P3,P4} /
// {P6,P7,P8}; every read's covering drain >=1 barrier earlier; every stage >=1
// barrier after its region's last LDS read (WAR). Prologue 7 pairs + VMC6
// primes steady state; last iter: VMC0@P4 covers the tail, stages P2..P8 skipped.
// MODE 1: +bias, GELU (tanh-form), bf16 out; MODE 2: +bias, fp32 out.
template <int MODE>
__device__ __forceinline__ void gemm8_body(
    const __bf16* __restrict__ A, int lda,
    const __bf16* __restrict__ B, int ldb,
    void* __restrict__ Cv, int ldc,
    const float* __restrict__ bias,
    int K, int n_tiles) {
    __shared__ char lds[131072];

    const int tid = threadIdx.x;
    const int lane = tid & 63;
    const int wave = tid >> 6;
    const int wm = wave >> 2;   // 0..1 -> 128 M-rows
    const int wn = wave & 3;    // 0..3 -> 64 N-cols

    int bid = blockIdx.x;
    const int nwg = gridDim.x;
    if ((nwg & 7) == 0) bid = (bid & 7) * (nwg >> 3) + (bid >> 3);
    const int bn = bid % n_tiles;
    const int bm = bid / n_tiles;
    const int m0 = bm * 256, n0 = bn * 256;

    // staging source map (frag-major; unchanged from r6..r10)
    const int rowA = ((tid >> 7) << 4) + (tid & 15);
    const int colA = (((tid >> 6) & 1) << 5) + (((tid >> 4) & 3) << 3);
    const int rowB = ((tid >> 6) << 4) + (tid & 15);
    const int colB = (((tid >> 4) & 3) << 3);
    const __bf16* Ag = A + (long)(m0 + rowA) * lda + colA;
    const __bf16* Bg = B + (long)(n0 + rowB) * ldb + colB;
    const int tid16 = tid * 16;

    // 32x32 fragment lane addressing within the 1KB-frag-major LDS
    const int laneA = ((lane >> 4) & 1) * 2048 + (lane >> 5) * 256 + (lane & 15) * 16;
    const int laneB = ((lane >> 4) & 1) * 1024 + (lane >> 5) * 256 + (lane & 15) * 16;
    const int bnh = wn >> 1;
    const int bno = (wn & 1) * 4096;

    f32x16 acc[4][2] = {};    // [qh*2+fm][fn], 128 AGPR
    bf16x8 af[2][2];          // [fm][h] — same-phase reads
    bf16x8 bfr[2][2][2];      // [kk][h][fn] — read at k-first-use, reused at q1

    const int nk = K >> 6;
    const int NI = nk >> 1;

#define STAGE_A(PAR, KT, MH, QH) \
    gload16(Ag + (long)(KT) * 64 + (long)((MH) * 128 + (QH) * 64) * lda, \
            lds + (PAR) * 32768 + (MH) * 16384 + (QH) * 8192 + tid16)
#define STAGE_B(PAR, KT, NH, KK) \
    gload16(Bg + (long)(KT) * 64 + (KK) * 32 + (long)((NH) * 128) * ldb, \
            lds + 65536 + (PAR) * 32768 + (NH) * 16384 + (KK) * 8192 + tid16)
#define VMC6 asm volatile("s_waitcnt vmcnt(6)" ::: "memory")
#define VMC0 asm volatile("s_waitcnt vmcnt(0)" ::: "memory")
#define BAR  __builtin_amdgcn_s_barrier()
#define LGKM0 asm volatile("s_waitcnt lgkmcnt(0)" ::: "memory")
#define RD_A32(PAR, QH, KK) { \
        const char* a_ = lds + (PAR) * 32768 + wm * 16384 + (QH) * 8192 + (KK) * 1024; \
        _Pragma("unroll") \
        for (int fm_ = 0; fm_ < 2; ++fm_) { \
            _Pragma("unroll") \
            for (int h_ = 0; h_ < 2; ++h_) \
                af[fm_][h_] = *(const bf16x8*)(a_ + fm_ * 4096 + h_ * 512 + laneA); } }
#define RD_B32(KK, PAR) { \
        const char* b_ = lds + 65536 + (PAR) * 32768 + bnh * 16384 + (KK) * 8192 + bno; \
        _Pragma("unroll") \
        for (int fn_ = 0; fn_ < 2; ++fn_) { \
            _Pragma("unroll") \
            for (int h_ = 0; h_ < 2; ++h_) \
                bfr[KK][h_][fn_] = *(const bf16x8*)(b_ + fn_ * 2048 + h_ * 512 + laneB); } }
#define MFMA8(QH, KK) { \
        __builtin_amdgcn_s_setprio(1); \
        _Pragma("unroll") \
        for (int h_ = 0; h_ < 2; ++h_) { \
            _Pragma("unroll") \
            for (int fm_ = 0; fm_ < 2; ++fm_) { \
                _Pragma("unroll") \
                for (int fn_ = 0; fn_ < 2; ++fn_) \
                    acc[(QH) * 2 + fm_][fn_] = __builtin_amdgcn_mfma_f32_32x32x16_bf16( \
                        af[fm_][h_], bfr[KK][h_][fn_], acc[(QH) * 2 + fm_][fn_], 0, 0, 0); } } \
        __builtin_amdgcn_s_setprio(0); }

    // prologue: pairs [1]=A(p0,q0,t0) [2]=B(p0,k0,t0) [3]=B(p0,k1,t0)
    // [4]=A(p0,q1,t0) [5]=A(p1,q0,t1) [6]=B(p1,k0,t1) [7]=B(p1,k1,t1);
    // VMC6 leaves {5,6,7} (drained at loop-P4), drains {1..4} (read P1..P4).
    STAGE_A(0, 0, 0, 0); STAGE_A(0, 0, 1, 0);
    STAGE_B(0, 0, 0, 0); STAGE_B(0, 0, 1, 0);
    STAGE_B(0, 0, 0, 1); STAGE_B(0, 0, 1, 1);
    STAGE_A(0, 0, 0, 1); STAGE_A(0, 0, 1, 1);
    STAGE_A(1, 1, 0, 0); STAGE_A(1, 1, 1, 0);
    STAGE_B(1, 1, 0, 0); STAGE_B(1, 1, 1, 0);
    STAGE_B(1, 1, 0, 1); STAGE_B(1, 1, 1, 1);
    VMC6;
    BAR;

    for (int I = 0; I < NI; ++I) {
        const int t = 2 * I;
        const bool nl = (I + 1 < NI);
        // P1: reads (p0,q0,k0); stage A(p1,q1,t+1)
        RD_B32(0, 0); RD_A32(0, 0, 0);
        STAGE_A(1, t + 1, 0, 1); STAGE_A(1, t + 1, 1, 1);
        BAR; LGKM0; MFMA8(0, 0); BAR;
        // P2: reads (p0,q0,k1); stage B(p0,k0,t+2)
        RD_B32(1, 0); RD_A32(0, 0, 1);
        if (nl) { STAGE_B(0, t + 2, 0, 0); STAGE_B(0, t + 2, 1, 0); }
        BAR; LGKM0; MFMA8(0, 1); BAR;
        // P3: reads (p0,q1,k0); stage A(p0,q0,t+2)
        RD_A32(0, 1, 0);
        if (nl) { STAGE_A(0, t + 2, 0, 0); STAGE_A(0, t + 2, 1, 0); }
        BAR; LGKM0; MFMA8(1, 0); BAR;
        // P4: reads (p0,q1,k1); stage B(p0,k1,t+2); DRAIN
        RD_A32(0, 1, 1);
        if (nl) { STAGE_B(0, t + 2, 0, 1); STAGE_B(0, t + 2, 1, 1); VMC6; } else { VMC0; }
        BAR; LGKM0; MFMA8(1, 1); BAR;
        // P5: reads (p1,q0,k0); stage A(p0,q1,t+2)
        RD_B32(0, 1); RD_A32(1, 0, 0);
        if (nl) { STAGE_A(0, t + 2, 0, 1); STAGE_A(0, t + 2, 1, 1); }
        BAR; LGKM0; MFMA8(0, 0); BAR;
        // P6: reads (p1,q0,k1); stage B(p1,k0,t+3)
        RD_B32(1, 1); RD_A32(1, 0, 1);
        if (nl) { STAGE_B(1, t + 3, 0, 0); STAGE_B(1, t + 3, 1, 0); }
        BAR; LGKM0; MFMA8(0, 1); BAR;
        // P7: reads (p1,q1,k0); stage A(p1,q0,t+3)
        RD_A32(1, 1, 0);
        if (nl) { STAGE_A(1, t + 3, 0, 0); STAGE_A(1, t + 3, 1, 0); }
        BAR; LGKM0; MFMA8(1, 0); BAR;
        // P8: reads (p1,q1,k1); stage B(p1,k1,t+3); DRAIN
        RD_A32(1, 1, 1);
        if (nl) { STAGE_B(1, t + 3, 0, 1); STAGE_B(1, t + 3, 1, 1); VMC6; }
        BAR; LGKM0; MFMA8(1, 1); BAR;
    }
#undef MFMA8
#undef RD_B32
#undef RD_A32
#undef LGKM0
#undef BAR
#undef VMC0
#undef VMC6
#undef STAGE_B
#undef STAGE_A

    // ---- epilogue: per-wave LDS remap (32 rows x 272B) -> coalesced stores
    // 32x32 C/D: col = lane&31, row = (reg&3) + 8*(reg>>2) + 4*(lane>>5)
    char* scr = lds + wave * 16384;
    const int col32 = lane & 31;
    const int rb5 = (lane >> 5) << 2;
    float bval[2];
    bval[0] = bias ? bias[n0 + wn * 64 + col32] : 0.0f;
    bval[1] = bias ? bias[n0 + wn * 64 + 32 + col32] : 0.0f;

    #pragma unroll
    for (int FM = 0; FM < 4; ++FM) {
        #pragma unroll
        for (int fn_ = 0; fn_ < 2; ++fn_) {
            #pragma unroll
            for (int rg = 0; rg < 16; ++rg) {
                float v = acc[FM][fn_][rg] + bval[fn_];
                if (MODE == 1) {
                    float u = v * (0.7978845608f + 0.0356774081f * v * v);
                    float e = __expf(-2.0f * fabsf(u));
                    float th = (1.0f - e) / (1.0f + e);
                    th = copysignf(th, u);
                    v = 0.5f * v * (1.0f + th);
                }
                int srow = (rg & 3) + ((rg >> 2) << 3) + rb5;
                *(float*)(scr + srow * 272 + (fn_ * 32 + col32) * 4) = v;
            }
        }
        asm volatile("s_waitcnt lgkmcnt(0)" ::: "memory");  // scratch RAW
        if (MODE == 2) {
            #pragma unroll
            for (int rep = 0; rep < 8; ++rep) {
                int row = rep * 4 + (lane >> 4);
                f32x4 val = *(const f32x4*)(scr + row * 272 + (lane & 15) * 16);
                long grow = (long)(m0 + wm * 128 + FM * 32 + row);
                *(f32x4*)&((float*)Cv)[grow * ldc + n0 + wn * 64 + (lane & 15) * 4] = val;
            }
        } else {
            #pragma unroll
            for (int rep = 0; rep < 4; ++rep) {
                int row = rep * 8 + (lane >> 3);
                f32x4 v0 = *(const f32x4*)(scr + row * 272 + (lane & 7) * 32);
                f32x4 v1 = *(const f32x4*)(scr + row * 272 + (lane & 7) * 32 + 16);
                bf16x8 o;
                o[0] = (__bf16)v0[0]; o[1] = (__bf16)v0[1]; o[2] = (__bf16)v0[2]; o[3] = (__bf16)v0[3];
                o[4] = (__bf16)v1[0]; o[5] = (__bf16)v1[1]; o[6] = (__bf16)v1[2]; o[7] = (__bf16)v1[3];
                long grow = (long)(m0 + wm * 128 + FM * 32 + row);
                *(bf16x8*)&((__bf16*)Cv)[grow * ldc + n0 + wn * 64 + (lane & 7) * 8] = o;
            }
        }
        asm volatile("s_waitcnt lgkmcnt(0)" ::: "memory");  // scratch WAR before next FM
    }
}

__global__ __launch_bounds__(512, 2) void k_g256_gelu(
    const __bf16* __restrict__ A, int lda, const __bf16* __restrict__ B, int ldb,
    void* __restrict__ Cv, int ldc, const float* __restrict__ bias, int K, int n_tiles) {
    gemm8_body<1>(A, lda, B, ldb, Cv, ldc, bias, K, n_tiles);
}
__global__ __launch_bounds__(512, 2) void k_g256_out(
    const __bf16* __restrict__ A, int lda, const __bf16* __restrict__ B, int ldb,
    void* __restrict__ Cv, int ldc, const float* __restrict__ bias, int K, int n_tiles) {
    gemm8_body<2>(A, lda, B, ldb, Cv, ldc, bias, K, n_tiles);
}

// ---------------- host ----------------
extern "C" void kernel_launch(void* const* d_in, const int* in_sizes, int n_in,
                              void* d_out, int out_size, void* d_ws, size_t ws_size,
                              hipStream_t stream) {
    constexpr int Bsz = 16384, F = 1024, GD = 512, TD = 768;
    constexpr int XLD = F + GD + TD;  // 2304

    const float* gnn = (const float*)d_in[0];
    const float* tr  = (const float*)d_in[1];
    const float* Wg  = (const float*)d_in[2];
    const float* bg  = (const float*)d_in[3];
    const float* Wt  = (const float*)d_in[4];
    const float* bt  = (const float*)d_in[5];
    const float* Wv  = (const float*)d_in[6];
    const float* bv  = (const float*)d_in[7];
    const float* Wo  = (const float*)d_in[8];
    const float* bo  = (const float*)d_in[9];
    const float* W1  = (const float*)d_in[10];
    const float* b1  = (const float*)d_in[11];
    const float* W2  = (const float*)d_in[12];
    const float* b2  = (const float*)d_in[13];
    float* out = (float*)d_out;

    char* w = (char*)d_ws;
    auto alloc = [&](size_t bytes) {
        char* p = w;
        w += (bytes + 255) & ~(size_t)255;
        return p;
    };
    __bf16* X    = (__bf16*)alloc((size_t)Bsz * XLD * 2);       // [h | gnn | tr]
    __bf16* M1   = (__bf16*)alloc((size_t)F * (GD + TD) * 2);   // [Mg | Mt]
    __bf16* Wp   = (__bf16*)alloc((size_t)F * XLD * 2);         // [W2 | Wg | Wt]
    __bf16* W1ab = (__bf16*)alloc((size_t)2 * F * F * 2);       // [W1a ; W1b]
    __bf16* Wv_b = (__bf16*)alloc((size_t)F * F * 2);
    __bf16* WoT  = (__bf16*)alloc((size_t)F * F * 2);
    __bf16* WgT  = (__bf16*)alloc((size_t)GD * F * 2);
    __bf16* WtT  = (__bf16*)alloc((size_t)TD * F * 2);
    __bf16* U12  = (__bf16*)alloc((size_t)2 * F * F * 2);       // [U1 ; U2]
    __bf16* VtT  = (__bf16*)alloc((size_t)TD * F * 2);
    __bf16* VgT  = (__bf16*)alloc((size_t)GD * F * 2);
    float* b_att = (float*)alloc(F * 4);
    float* vb_t  = (float*)alloc(F * 4);
    float* vb_g  = (float*)alloc(F * 4);
    float* bz2   = (float*)alloc(F * 4);
    float* b_out = (float*)alloc(F * 4);
    if ((size_t)(w - (char*)d_ws) > ws_size) return;

    dim3 b256(256);

    // all converts + transposes, one launch
    k_prep<<<dim3(15232), b256, 0, stream>>>(gnn, tr, Wo, W1, W2, Wg, Wt, Wv,
                                             X, W1ab, Wp, Wv_b, WoT, WgT, WtT);
    // all bias dot-products, one launch (inputs only)
    k_bias1<<<dim3(3072), b256, 0, stream>>>(Wo, bv, bo, Wv, bt, bg, b_att, vb_t, vb_g);

    // level-1 weight composition (4 GEMMs batched)
    k_gemmL1<<<dim3(832), b256, 0, stream>>>(W1ab, WoT, WtT, WgT, Wv_b, U12, VtT, VgT);

    // bz2 from U12
    k_bias_z2<<<dim3(F), b256, 0, stream>>>(W1, b_att, b1, U12, vb_t, vb_g, bt, bg, b2,
                                            bz2, b_out);

    // level-2 weight composition (2 GEMMs batched) -> M1
    k_gemmL2<<<dim3(320), b256, 0, stream>>>(U12, VtT, VgT, M1);

    // pass 1: h = gelu([gnn|tr] @ M1^T + bz2) -> X[:, 0:1024] (bf16)   K=1280
    k_g256_gelu<<<dim3((Bsz / 256) * (F / 256)), dim3(512), 0, stream>>>(
        X + F, XLD, M1, GD + TD, X, XLD, bz2, GD + TD, F / 256);

    // pass 2: out = [h|gnn|tr] @ [W2|Wg|Wt]^T + b_out (fp32)           K=2304
    k_g256_out<<<dim3((Bsz / 256) * (F / 256)), dim3(512), 0, stream>>>(
        X, XLD, Wp, XLD, out, F, b_out, XLD, F / 256);
}